// Round 2
// baseline (14543.715 us; speedup 1.0000x reference)
//
#include <hip/hip_runtime.h>
#include <hip/hip_bf16.h>
#include <math.h>

#define Bb 1024
#define Tt 15
#define Ii 256
#define Hh 512
#define Ff 8
#define Gg 2048  // 4*Hh

__device__ __forceinline__ float sigmoidf_(float x) { return 1.0f / (1.0f + expf(-x)); }

__device__ __forceinline__ float bf2f(unsigned short u) {
    return __uint_as_float(((unsigned int)u) << 16);
}
__device__ __forceinline__ unsigned short f2bf(float f) {
    unsigned int u = __float_as_uint(f);
    u += 0x7fffu + ((u >> 16) & 1u);   // round-to-nearest-even
    return (unsigned short)(u >> 16);
}

// ---------------- Fused LSTM step: gates = x_t @ Wih^T + h_prev @ Whh^T + b, then cell ----------------
// Block 256 thr. Tile: 64 batch x 16 h (x4 gates). h state in bf16, cell state fp32.
template<int KIN, bool XBF16>
__global__ __launch_bounds__(256) void lstm_step_kernel(
    const void* __restrict__ xbase_v, long xRowStride, long xHeadStride,
    const float* __restrict__ Wih, const float* __restrict__ Whh,
    const float* __restrict__ bias,
    const unsigned short* __restrict__ hprev, unsigned short* __restrict__ hnext,
    float* __restrict__ cbuf)
{
    const int f   = blockIdx.z;
    const int hh0 = blockIdx.y * 16;
    const int b0  = blockIdx.x * 64;
    const int tid = threadIdx.x;
    const int tx  = tid & 15;   // h within tile
    const int ty  = tid >> 4;   // 16 groups of 4 batch rows
    const int hh  = hh0 + tx;

    __shared__ float xs[64][36];
    __shared__ float wsm[64][36];

    float acc[4][4];
#pragma unroll
    for (int g = 0; g < 4; ++g) {
        const float bv = bias[(size_t)f * Gg + g * Hh + hh];
#pragma unroll
        for (int r = 0; r < 4; ++r) acc[g][r] = bv;
    }

    const int row  = tid >> 2;        // 0..63
    const int kk   = (tid & 3) * 8;   // 0,8,16,24
    const int gate = row >> 4, rr = row & 15;

#pragma unroll
    for (int phase = 0; phase < 2; ++phase) {
        const int K = (phase == 0) ? KIN : Hh;
        const float* W = (phase == 0) ? Wih : Whh;
        const float* wrow = W + ((size_t)f * Gg + gate * Hh + hh0 + rr) * K;

        for (int kb = 0; kb < K; kb += 32) {
            if (phase == 0 && !XBF16) {
                const float* src = ((const float*)xbase_v) + (size_t)f * xHeadStride
                                   + (size_t)(b0 + row) * xRowStride + kb + kk;
                float4 v0 = ((const float4*)src)[0];
                float4 v1 = ((const float4*)src)[1];
                *(float4*)&xs[row][kk]     = v0;
                *(float4*)&xs[row][kk + 4] = v1;
            } else {
                const unsigned short* src = (phase == 0)
                    ? ((const unsigned short*)xbase_v) + (size_t)f * xHeadStride
                        + (size_t)(b0 + row) * xRowStride + kb + kk
                    : hprev + (size_t)f * Bb * Hh + (size_t)(b0 + row) * Hh + kb + kk;
                union { float4 f4; unsigned short u[8]; } ld;
                ld.f4 = *(const float4*)src;
#pragma unroll
                for (int j = 0; j < 8; ++j) xs[row][kk + j] = bf2f(ld.u[j]);
            }
            {
                const float4* q4 = (const float4*)(wrow + kb + kk);
                float4 w0 = q4[0], w1 = q4[1];
                *(float4*)&wsm[row][kk]     = w0;
                *(float4*)&wsm[row][kk + 4] = w1;
            }
            __syncthreads();
#pragma unroll
            for (int k4 = 0; k4 < 8; ++k4) {
                float4 xv[4], wv[4];
#pragma unroll
                for (int r = 0; r < 4; ++r) xv[r] = *(const float4*)&xs[ty * 4 + r][k4 * 4];
#pragma unroll
                for (int g = 0; g < 4; ++g) wv[g] = *(const float4*)&wsm[g * 16 + tx][k4 * 4];
#pragma unroll
                for (int g = 0; g < 4; ++g)
#pragma unroll
                    for (int r = 0; r < 4; ++r) {
                        acc[g][r] += wv[g].x * xv[r].x;
                        acc[g][r] += wv[g].y * xv[r].y;
                        acc[g][r] += wv[g].z * xv[r].z;
                        acc[g][r] += wv[g].w * xv[r].w;
                    }
            }
            __syncthreads();
        }
    }

    // cell update: each (f,b,hh) owned by exactly one thread; c fp32 in-place, h bf16 double-buffered
#pragma unroll
    for (int r = 0; r < 4; ++r) {
        const int b = b0 + ty * 4 + r;
        const size_t idx = (size_t)f * Bb * Hh + (size_t)b * Hh + hh;
        const float cold = cbuf[idx];
        const float iv = sigmoidf_(acc[0][r]);
        const float fv = sigmoidf_(acc[1][r]);
        const float gv = tanhf(acc[2][r]);
        const float ov = sigmoidf_(acc[3][r]);
        const float cn = fv * cold + iv * gv;
        const float hv = ov * tanhf(cn);
        cbuf[idx]  = cn;
        hnext[idx] = f2bf(hv);
    }
}

// ---------------- A1 projection: htmp[f,b,t,o] = h1[f,b,:] @ A1[o,:] + c1[o]  (bf16 in/out) ----------------
__global__ __launch_bounds__(256) void proj_kernel(
    const unsigned short* __restrict__ h1, const float* __restrict__ A1,
    const float* __restrict__ c1, unsigned short* __restrict__ htmp, int t)
{
    const int f  = blockIdx.z;
    const int o0 = blockIdx.y * 64;
    const int b0 = blockIdx.x * 64;
    const int tid = threadIdx.x;
    const int tx = tid & 15;
    const int ty = tid >> 4;

    __shared__ float xs[64][36];
    __shared__ float wsm[64][36];

    float acc[4][4] = {};

    const int row = tid >> 2;
    const int kk  = (tid & 3) * 8;

    for (int kb = 0; kb < Hh; kb += 32) {
        {
            const unsigned short* src = h1 + (size_t)f * Bb * Hh + (size_t)(b0 + row) * Hh + kb + kk;
            union { float4 f4; unsigned short u[8]; } ld;
            ld.f4 = *(const float4*)src;
#pragma unroll
            for (int j = 0; j < 8; ++j) xs[row][kk + j] = bf2f(ld.u[j]);

            const float4* q4 = (const float4*)(A1 + (size_t)(o0 + row) * Hh + kb + kk);
            float4 w0 = q4[0], w1 = q4[1];
            *(float4*)&wsm[row][kk]     = w0;
            *(float4*)&wsm[row][kk + 4] = w1;
        }
        __syncthreads();
#pragma unroll
        for (int k4 = 0; k4 < 8; ++k4) {
            float4 xv[4], wv[4];
#pragma unroll
            for (int r = 0; r < 4; ++r) xv[r] = *(const float4*)&xs[ty * 4 + r][k4 * 4];
#pragma unroll
            for (int g = 0; g < 4; ++g) wv[g] = *(const float4*)&wsm[g * 16 + tx][k4 * 4];
#pragma unroll
            for (int g = 0; g < 4; ++g)
#pragma unroll
                for (int r = 0; r < 4; ++r) {
                    acc[g][r] += wv[g].x * xv[r].x;
                    acc[g][r] += wv[g].y * xv[r].y;
                    acc[g][r] += wv[g].z * xv[r].z;
                    acc[g][r] += wv[g].w * xv[r].w;
                }
        }
        __syncthreads();
    }

#pragma unroll
    for (int g = 0; g < 4; ++g) {
        const int o = o0 + g * 16 + tx;
        const float cv = c1[o];
#pragma unroll
        for (int r = 0; r < 4; ++r) {
            const int b = b0 + ty * 4 + r;
            htmp[(((size_t)f * Bb + b) * Tt + t) * Hh + o] = f2bf(acc[g][r] + cv);
        }
    }
}

// ---------------- BN stats: per (f,t) sum/sumsq over (B,H), two-stage deterministic ----------------
__global__ __launch_bounds__(256) void stats_partial_kernel(
    const unsigned short* __restrict__ htmp, float* __restrict__ part)
{
    const int idx = blockIdx.x;            // f*(Tt*8) + t*8 + s
    const int s = idx & 7;
    const int t = (idx >> 3) % Tt;
    const int f = idx / (Tt * 8);
    const int tid = threadIdx.x;

    float sum = 0.f, ssq = 0.f;
    for (int bi = 0; bi < 128; ++bi) {
        const int b = s * 128 + bi;
        const ushort2 v = *(const ushort2*)(htmp + (((size_t)f * Bb + b) * Tt + t) * Hh + tid * 2);
        const float x = bf2f(v.x), y = bf2f(v.y);
        sum += x + y;
        ssq += x * x + y * y;
    }
    __shared__ float rs[256], rq[256];
    rs[tid] = sum; rq[tid] = ssq;
    __syncthreads();
    for (int s2 = 128; s2 > 0; s2 >>= 1) {
        if (tid < s2) { rs[tid] += rs[tid + s2]; rq[tid] += rq[tid + s2]; }
        __syncthreads();
    }
    if (tid == 0) { part[idx * 2] = rs[0]; part[idx * 2 + 1] = rq[0]; }
}

__global__ void stats_combine_kernel(const float* __restrict__ part, float* __restrict__ stats)
{
    const int i = threadIdx.x;
    if (i < Ff * Tt) {
        float s = 0.f, q = 0.f;
        for (int j = 0; j < 8; ++j) { s += part[(i * 8 + j) * 2]; q += part[(i * 8 + j) * 2 + 1]; }
        const float n = (float)((size_t)Bb * Hh);
        const float mean = s / n;
        const float var  = q / n - mean * mean;
        stats[i * 2]     = mean;
        stats[i * 2 + 1] = rsqrtf(var + 1e-5f);
    }
}

// ---------------- Output: out[b,t,f] = sum_o relu(bn(htmp)) * A2[o] + c2 ----------------
__global__ __launch_bounds__(256) void out_kernel(
    const unsigned short* __restrict__ htmp, const float* __restrict__ stats,
    const float* __restrict__ gamma, const float* __restrict__ beta,
    const float* __restrict__ A2, const float* __restrict__ c2,
    float* __restrict__ out)
{
    const int wave = threadIdx.x >> 6;
    const int lane = threadIdx.x & 63;
    const size_t row = (size_t)blockIdx.x * 4 + wave;   // (f*B + b)*T + t
    const int t = (int)(row % Tt);
    const size_t fb = row / Tt;
    const int b = (int)(fb % Bb);
    const int f = (int)(fb / Bb);

    const float mean = stats[(f * Tt + t) * 2];
    const float inv  = stats[(f * Tt + t) * 2 + 1];
    const float ga = gamma[t], be = beta[t];
    const unsigned short* hrow = htmp + row * Hh;

    union { float4 f4; unsigned short u[8]; } hv;
    hv.f4 = *(const float4*)(hrow + lane * 8);
    const float4 a0 = *(const float4*)(A2 + lane * 8);
    const float4 a1 = *(const float4*)(A2 + lane * 8 + 4);
    const float a2v[8] = {a0.x, a0.y, a0.z, a0.w, a1.x, a1.y, a1.z, a1.w};

    float acc = 0.f;
#pragma unroll
    for (int j = 0; j < 8; ++j) {
        const float x = (bf2f(hv.u[j]) - mean) * inv * ga + be;
        acc += fmaxf(x, 0.f) * a2v[j];
    }
#pragma unroll
    for (int off = 32; off > 0; off >>= 1) acc += __shfl_down(acc, off);
    if (lane == 0) out[(size_t)b * Tt * Ff + (size_t)t * Ff + f] = acc + c2[0];
}

extern "C" void kernel_launch(void* const* d_in, const int* in_sizes, int n_in,
                              void* d_out, int out_size, void* d_ws, size_t ws_size,
                              hipStream_t stream) {
    const float* X     = (const float*)d_in[0];
    const float* Wih0  = (const float*)d_in[1];
    const float* Whh0  = (const float*)d_in[2];
    const float* b0p   = (const float*)d_in[3];
    const float* Wih1  = (const float*)d_in[4];
    const float* Whh1  = (const float*)d_in[5];
    const float* b1p   = (const float*)d_in[6];
    const float* A1    = (const float*)d_in[7];
    const float* c1v   = (const float*)d_in[8];
    const float* gamma = (const float*)d_in[9];
    const float* beta  = (const float*)d_in[10];
    const float* A2    = (const float*)d_in[11];
    const float* c2    = (const float*)d_in[12];
    float* out = (float*)d_out;

    // ---- workspace layout (bytes) ----
    // [0,16M)   c0 fp32        [16M,32M)  c1 fp32
    // [32M,40M) h0A bf16       [40M,48M)  h1A bf16
    // [48M,56M) h0B bf16       [56M,64M)  h1B bf16
    // [64M, 64M+125829120) htmp bf16 [F,B,T,H]
    // then part (1920 f32), stats (240 f32).  Total ~193 MB.
    char* ws = (char*)d_ws;
    const size_t FBH = (size_t)Ff * Bb * Hh;                 // 4,194,304
    float* c0buf = (float*)(ws);
    float* c1buf = (float*)(ws + FBH * 4);
    unsigned short* h0A = (unsigned short*)(ws + FBH * 8);
    unsigned short* h1A = (unsigned short*)(ws + FBH * 8 + FBH * 2);
    unsigned short* h0B = (unsigned short*)(ws + FBH * 8 + FBH * 4);
    unsigned short* h1B = (unsigned short*)(ws + FBH * 8 + FBH * 6);
    unsigned short* htmp = (unsigned short*)(ws + FBH * 16);
    const size_t FBTH = (size_t)Ff * Bb * Tt * Hh;           // 62,914,560
    float* part  = (float*)(ws + FBH * 16 + FBTH * 2);
    float* stats = part + Ff * Tt * 8 * 2;

    // zero c0,c1 (fp32) and h0A,h1A (bf16): contiguous [0, 12*FBH bytes)
    hipMemsetAsync(ws, 0, FBH * 12, stream);

    const dim3 blk(256);
    const dim3 gstep(Bb / 64, Hh / 16, Ff);
    const dim3 gproj(Bb / 64, Hh / 64, Ff);

    for (int t = 0; t < Tt; ++t) {
        unsigned short* hp0 = (t & 1) ? h0B : h0A;
        unsigned short* hn0 = (t & 1) ? h0A : h0B;
        unsigned short* hp1 = (t & 1) ? h1B : h1A;
        unsigned short* hn1 = (t & 1) ? h1A : h1B;

        lstm_step_kernel<Ii, false><<<gstep, blk, 0, stream>>>(
            (const void*)(X + (size_t)t * Ii), (long)Tt * Ii, 0L,
            Wih0, Whh0, b0p, hp0, hn0, c0buf);

        lstm_step_kernel<Hh, true><<<gstep, blk, 0, stream>>>(
            (const void*)hn0, (long)Hh, (long)(Bb * Hh),
            Wih1, Whh1, b1p, hp1, hn1, c1buf);

        proj_kernel<<<gproj, blk, 0, stream>>>(hn1, A1, c1v, htmp, t);
    }

    stats_partial_kernel<<<dim3(Ff * Tt * 8), blk, 0, stream>>>(htmp, part);
    stats_combine_kernel<<<dim3(1), dim3(128), 0, stream>>>(part, stats);
    out_kernel<<<dim3(Ff * Bb * Tt / 4), blk, 0, stream>>>(htmp, stats, gamma, beta, A2, c2, out);
    (void)in_sizes; (void)n_in; (void)out_size; (void)ws_size;
}

// Round 3
// 2323.440 us; speedup vs baseline: 6.2596x; 6.2596x over previous
//
#include <hip/hip_runtime.h>
#include <hip/hip_bf16.h>
#include <math.h>

#define Bb 1024
#define Tt 15
#define Ii 256
#define Hh 512
#define Ff 8
#define Gg 2048  // 4*Hh

typedef __attribute__((ext_vector_type(8))) short short8v;
typedef __attribute__((ext_vector_type(4))) float f32x4;

__device__ __forceinline__ float sigmoidf_(float x) { return 1.0f / (1.0f + expf(-x)); }
__device__ __forceinline__ float bf2f(unsigned short u) {
    return __uint_as_float(((unsigned int)u) << 16);
}
__device__ __forceinline__ unsigned short f2bf(float f) {
    unsigned int u = __float_as_uint(f);
    u += 0x7fffu + ((u >> 16) & 1u);   // RNE
    return (unsigned short)(u >> 16);
}

// ---------------- fp32 -> bf16 conversion (n8 = n/8) ----------------
__global__ __launch_bounds__(256) void cvt_kernel(const float* __restrict__ in,
                                                  unsigned short* __restrict__ out, int n8) {
    const int i = blockIdx.x * 256 + threadIdx.x;
    if (i < n8) {
        const float4 v0 = ((const float4*)in)[i * 2];
        const float4 v1 = ((const float4*)in)[i * 2 + 1];
        union { unsigned short u[8]; short8v v; } ob;
        ob.u[0] = f2bf(v0.x); ob.u[1] = f2bf(v0.y); ob.u[2] = f2bf(v0.z); ob.u[3] = f2bf(v0.w);
        ob.u[4] = f2bf(v1.x); ob.u[5] = f2bf(v1.y); ob.u[6] = f2bf(v1.z); ob.u[7] = f2bf(v1.w);
        *(short8v*)&out[(size_t)i * 8] = ob.v;
    }
}

// ---------------- MFMA step kernel ----------------
// MODE 0: layer-0 LSTM step   (x from Xbf K=256, h from ybuf slice t-1 K=512) -> ybuf slice t
// MODE 1: layer-1 LSTM step   (x from ybuf slice t K=512, h from h1 dbuf K=512) -> h1 dbuf
// MODE 2: proj                (x = h1 cur K=512, W = A1bf) -> htmp(=ybuf) slice t
// Tile: 128 batch x 128 cols (modes 0/1: 4 gates x 32 h; mode 2: 128 o). 4 waves, BK=32.
template<int MODE, bool FIRST>
__global__ __launch_bounds__(256) void step_mfma(
    const short* Xbf, const short* ysrc, short* ydst,
    const short* hsrc, short* hdst,
    const short* __restrict__ Wx, const short* __restrict__ Wh,
    const float* __restrict__ bias, float* __restrict__ cbuf,
    unsigned short* htmp, int t)
{
    const int f  = blockIdx.z;
    const int b0 = blockIdx.x * 128;
    const int h0 = blockIdx.y * ((MODE == 2) ? 128 : 32);
    const int tid = threadIdx.x;
    const int wave = tid >> 6, lane = tid & 63;
    const int wm = (wave >> 1) * 64, wn = (wave & 1) * 64;

    __shared__ __align__(16) char smem[128 * 130 * 4];  // 66560 B
    short* sA = (short*)smem;           // [128][40] bf16
    short* sB = sA + 128 * 40;          // [128][40] bf16
    float* gt = (float*)smem;           // [128][130] f32 (epilogue, aliases staging)

    f32x4 acc[4][4];
#pragma unroll
    for (int i = 0; i < 4; ++i)
#pragma unroll
        for (int j = 0; j < 4; ++j) acc[i][j] = (f32x4){0.f, 0.f, 0.f, 0.f};

    const int srow = tid >> 2, spart = (tid & 3) * 8;
    const int frow = lane & 15, fk = (lane >> 4) * 8;

    auto phase = [&](const short* abase, long arstride, const short* wbase, int K) {
        for (int kb = 0; kb < K; kb += 32) {
#pragma unroll
            for (int s = 0; s < 2; ++s) {
                const int row = srow + s * 64;
                *(short8v*)&sA[row * 40 + spart] =
                    *(const short8v*)(abase + (size_t)row * arstride + kb + spart);
                const int wr = (MODE == 2) ? (h0 + row) : ((row >> 5) * Hh + h0 + (row & 31));
                *(short8v*)&sB[row * 40 + spart] =
                    *(const short8v*)(wbase + (size_t)wr * K + kb + spart);
            }
            __syncthreads();
            short8v av[4], bv[4];
#pragma unroll
            for (int i = 0; i < 4; ++i) av[i] = *(const short8v*)&sA[(wm + i * 16 + frow) * 40 + fk];
#pragma unroll
            for (int j = 0; j < 4; ++j) bv[j] = *(const short8v*)&sB[(wn + j * 16 + frow) * 40 + fk];
#pragma unroll
            for (int i = 0; i < 4; ++i)
#pragma unroll
                for (int j = 0; j < 4; ++j)
                    acc[i][j] = __builtin_amdgcn_mfma_f32_16x16x32_bf16(av[i], bv[j], acc[i][j], 0, 0, 0);
            __syncthreads();
        }
    };

    if (MODE == 0) {
        phase(Xbf + ((size_t)b0 * Tt + t) * Ii, (long)Tt * Ii, Wx + (size_t)f * Gg * Ii, Ii);
        if (!FIRST)
            phase(ysrc + (((size_t)f * Bb + b0) * Tt + (t - 1)) * Hh, (long)Tt * Hh,
                  Wh + (size_t)f * Gg * Hh, Hh);
    } else if (MODE == 1) {
        phase(ysrc + (((size_t)f * Bb + b0) * Tt + t) * Hh, (long)Tt * Hh,
              Wx + (size_t)f * Gg * Hh, Hh);
        if (!FIRST)
            phase(hsrc + ((size_t)f * Bb + b0) * Hh, (long)Hh, Wh + (size_t)f * Gg * Hh, Hh);
    } else {
        phase(hsrc + ((size_t)f * Bb + b0) * Hh, (long)Hh, Wx, Hh);
    }

    // spill acc to LDS f32 tile (stride 130 -> 2-way max on banks)
#pragma unroll
    for (int i = 0; i < 4; ++i)
#pragma unroll
        for (int j = 0; j < 4; ++j)
#pragma unroll
            for (int r = 0; r < 4; ++r)
                gt[(wm + i * 16 + (lane >> 4) * 4 + r) * 130 + wn + j * 16 + (lane & 15)] = acc[i][j][r];
    __syncthreads();

    if (MODE != 2) {
        const int hl = tid & 31, bg = tid >> 5;
        float bi[4];
#pragma unroll
        for (int g = 0; g < 4; ++g) bi[g] = bias[(size_t)f * Gg + g * Hh + h0 + hl];
#pragma unroll
        for (int ii = 0; ii < 16; ++ii) {
            const int bl = bg * 16 + ii;
            const int b = b0 + bl;
            const float gi = gt[bl * 130 +      hl] + bi[0];
            const float gf = gt[bl * 130 + 32 + hl] + bi[1];
            const float gg = gt[bl * 130 + 64 + hl] + bi[2];
            const float go = gt[bl * 130 + 96 + hl] + bi[3];
            const size_t cidx = ((size_t)f * Bb + b) * Hh + h0 + hl;
            const float cold = FIRST ? 0.f : cbuf[cidx];
            const float cn = sigmoidf_(gf) * cold + sigmoidf_(gi) * tanhf(gg);
            const float hv = sigmoidf_(go) * tanhf(cn);
            cbuf[cidx] = cn;
            const unsigned short hb = f2bf(hv);
            if (MODE == 0)
                ((unsigned short*)ydst)[(((size_t)f * Bb + b) * Tt + t) * Hh + h0 + hl] = hb;
            else
                ((unsigned short*)hdst)[cidx] = hb;
        }
    } else {
        const int rowl = tid >> 1, half = tid & 1;
        const int b = b0 + rowl;
#pragma unroll
        for (int cc = 0; cc < 64; cc += 8) {
            union { unsigned short u[8]; short8v v; } ob;
#pragma unroll
            for (int u = 0; u < 8; ++u) {
                const int o = half * 64 + cc + u;
                ob.u[u] = f2bf(gt[rowl * 130 + o] + bias[h0 + o]);
            }
            *(short8v*)&htmp[(((size_t)f * Bb + b) * Tt + t) * Hh + h0 + half * 64 + cc] = ob.v;
        }
    }
}

// ---------------- BN stats: per (f,t) sum/sumsq over (B,H), two-stage deterministic ----------------
__global__ __launch_bounds__(256) void stats_partial_kernel(
    const unsigned short* __restrict__ htmp, float* __restrict__ part)
{
    const int idx = blockIdx.x;            // f*(Tt*8) + t*8 + s
    const int s = idx & 7;
    const int t = (idx >> 3) % Tt;
    const int f = idx / (Tt * 8);
    const int tid = threadIdx.x;

    float sum = 0.f, ssq = 0.f;
    for (int bi = 0; bi < 128; ++bi) {
        const int b = s * 128 + bi;
        const ushort2 v = *(const ushort2*)(htmp + (((size_t)f * Bb + b) * Tt + t) * Hh + tid * 2);
        const float x = bf2f(v.x), y = bf2f(v.y);
        sum += x + y;
        ssq += x * x + y * y;
    }
    __shared__ float rs[256], rq[256];
    rs[tid] = sum; rq[tid] = ssq;
    __syncthreads();
    for (int s2 = 128; s2 > 0; s2 >>= 1) {
        if (tid < s2) { rs[tid] += rs[tid + s2]; rq[tid] += rq[tid + s2]; }
        __syncthreads();
    }
    if (tid == 0) { part[idx * 2] = rs[0]; part[idx * 2 + 1] = rq[0]; }
}

__global__ void stats_combine_kernel(const float* __restrict__ part, float* __restrict__ stats)
{
    const int i = threadIdx.x;
    if (i < Ff * Tt) {
        float s = 0.f, q = 0.f;
        for (int j = 0; j < 8; ++j) { s += part[(i * 8 + j) * 2]; q += part[(i * 8 + j) * 2 + 1]; }
        const float n = (float)((size_t)Bb * Hh);
        const float mean = s / n;
        const float var  = q / n - mean * mean;
        stats[i * 2]     = mean;
        stats[i * 2 + 1] = rsqrtf(var + 1e-5f);
    }
}

// ---------------- Output: out[b,t,f] = sum_o relu(bn(htmp)) * A2[o] + c2 ----------------
__global__ __launch_bounds__(256) void out_kernel(
    const unsigned short* __restrict__ htmp, const float* __restrict__ stats,
    const float* __restrict__ gamma, const float* __restrict__ beta,
    const float* __restrict__ A2, const float* __restrict__ c2,
    float* __restrict__ out)
{
    const int wave = threadIdx.x >> 6;
    const int lane = threadIdx.x & 63;
    const size_t row = (size_t)blockIdx.x * 4 + wave;   // (f*B + b)*T + t
    const int t = (int)(row % Tt);
    const size_t fb = row / Tt;
    const int b = (int)(fb % Bb);
    const int f = (int)(fb / Bb);

    const float mean = stats[(f * Tt + t) * 2];
    const float inv  = stats[(f * Tt + t) * 2 + 1];
    const float ga = gamma[t], be = beta[t];
    const unsigned short* hrow = htmp + row * Hh;

    union { float4 f4; unsigned short u[8]; } hv;
    hv.f4 = *(const float4*)(hrow + lane * 8);
    const float4 a0 = *(const float4*)(A2 + lane * 8);
    const float4 a1 = *(const float4*)(A2 + lane * 8 + 4);
    const float a2v[8] = {a0.x, a0.y, a0.z, a0.w, a1.x, a1.y, a1.z, a1.w};

    float acc = 0.f;
#pragma unroll
    for (int j = 0; j < 8; ++j) {
        const float x = (bf2f(hv.u[j]) - mean) * inv * ga + be;
        acc += fmaxf(x, 0.f) * a2v[j];
    }
#pragma unroll
    for (int off = 32; off > 0; off >>= 1) acc += __shfl_down(acc, off);
    if (lane == 0) out[(size_t)b * Tt * Ff + (size_t)t * Ff + f] = acc + c2[0];
}

extern "C" void kernel_launch(void* const* d_in, const int* in_sizes, int n_in,
                              void* d_out, int out_size, void* d_ws, size_t ws_size,
                              hipStream_t stream) {
    const float* X     = (const float*)d_in[0];
    const float* Wih0  = (const float*)d_in[1];
    const float* Whh0  = (const float*)d_in[2];
    const float* b0p   = (const float*)d_in[3];
    const float* Wih1  = (const float*)d_in[4];
    const float* Whh1  = (const float*)d_in[5];
    const float* b1p   = (const float*)d_in[6];
    const float* A1    = (const float*)d_in[7];
    const float* c1v   = (const float*)d_in[8];
    const float* gamma = (const float*)d_in[9];
    const float* beta  = (const float*)d_in[10];
    const float* A2    = (const float*)d_in[11];
    const float* c2    = (const float*)d_in[12];
    float* out = (float*)d_out;

    // ---- workspace layout (bytes), total ~216 MiB ----
    char* ws = (char*)d_ws;
    size_t off = 0;
    short* Xbf    = (short*)(ws + off); off += (size_t)Bb * Tt * Ii * 2;        // 7,864,320
    short* Wih0bf = (short*)(ws + off); off += (size_t)Ff * Gg * Ii * 2;        // 8,388,608
    short* Whh0bf = (short*)(ws + off); off += (size_t)Ff * Gg * Hh * 2;        // 16,777,216
    short* Wih1bf = (short*)(ws + off); off += (size_t)Ff * Gg * Hh * 2;
    short* Whh1bf = (short*)(ws + off); off += (size_t)Ff * Gg * Hh * 2;
    short* A1bf   = (short*)(ws + off); off += (size_t)Hh * Hh * 2;             // 524,288
    short* ybuf   = (short*)(ws + off); off += (size_t)Ff * Bb * Tt * Hh * 2;   // 125,829,120
    short* h1A    = (short*)(ws + off); off += (size_t)Ff * Bb * Hh * 2;
    short* h1B    = (short*)(ws + off); off += (size_t)Ff * Bb * Hh * 2;
    float* cbuf   = (float*)(ws + off); off += (size_t)Ff * Bb * Hh * 4;        // 16,777,216
    float* part   = (float*)(ws + off); off += (size_t)Ff * Tt * 8 * 2 * 4;
    float* stats  = (float*)(ws + off); off += (size_t)Ff * Tt * 2 * 4;

    const dim3 blk(256);
    // converts
    cvt_kernel<<<dim3((Bb * Tt * Ii / 8 + 255) / 256), blk, 0, stream>>>(X, (unsigned short*)Xbf, Bb * Tt * Ii / 8);
    cvt_kernel<<<dim3((Ff * Gg * Ii / 8 + 255) / 256), blk, 0, stream>>>(Wih0, (unsigned short*)Wih0bf, Ff * Gg * Ii / 8);
    cvt_kernel<<<dim3((Ff * Gg * Hh / 8 + 255) / 256), blk, 0, stream>>>(Whh0, (unsigned short*)Whh0bf, Ff * Gg * Hh / 8);
    cvt_kernel<<<dim3((Ff * Gg * Hh / 8 + 255) / 256), blk, 0, stream>>>(Wih1, (unsigned short*)Wih1bf, Ff * Gg * Hh / 8);
    cvt_kernel<<<dim3((Ff * Gg * Hh / 8 + 255) / 256), blk, 0, stream>>>(Whh1, (unsigned short*)Whh1bf, Ff * Gg * Hh / 8);
    cvt_kernel<<<dim3((Hh * Hh / 8 + 255) / 256), blk, 0, stream>>>(A1, (unsigned short*)A1bf, Hh * Hh / 8);

    const dim3 gstep(Bb / 128, Hh / 32, Ff);   // 8 x 16 x 8
    const dim3 gproj(Bb / 128, Hh / 128, Ff);  // 8 x 4 x 8

    // layer 0: all timesteps, writes ybuf[f,b,t,:]
    for (int t = 0; t < Tt; ++t) {
        if (t == 0)
            step_mfma<0, true><<<gstep, blk, 0, stream>>>(Xbf, ybuf, ybuf, nullptr, nullptr,
                Wih0bf, Whh0bf, b0p, cbuf, nullptr, t);
        else
            step_mfma<0, false><<<gstep, blk, 0, stream>>>(Xbf, ybuf, ybuf, nullptr, nullptr,
                Wih0bf, Whh0bf, b0p, cbuf, nullptr, t);
    }

    // layer 1 + proj: step t reads ybuf slice t, proj overwrites ybuf slice t (stream-ordered)
    for (int t = 0; t < Tt; ++t) {
        short* hn = (t & 1) ? h1A : h1B;
        short* hp = (t & 1) ? h1B : h1A;
        if (t == 0)
            step_mfma<1, true><<<gstep, blk, 0, stream>>>(nullptr, ybuf, nullptr, hp, hn,
                Wih1bf, Whh1bf, b1p, cbuf, nullptr, t);
        else
            step_mfma<1, false><<<gstep, blk, 0, stream>>>(nullptr, ybuf, nullptr, hp, hn,
                Wih1bf, Whh1bf, b1p, cbuf, nullptr, t);
        step_mfma<2, false><<<gproj, blk, 0, stream>>>(nullptr, nullptr, nullptr, hn, nullptr,
            A1bf, nullptr, c1v, cbuf, (unsigned short*)ybuf, t);
    }

    stats_partial_kernel<<<dim3(Ff * Tt * 8), blk, 0, stream>>>((const unsigned short*)ybuf, part);
    stats_combine_kernel<<<dim3(1), dim3(128), 0, stream>>>(part, stats);
    out_kernel<<<dim3(Ff * Bb * Tt / 4), blk, 0, stream>>>((const unsigned short*)ybuf, stats,
        gamma, beta, A2, c2, out);
    (void)in_sizes; (void)n_in; (void)out_size; (void)ws_size;
}

// Round 4
// 1783.163 us; speedup vs baseline: 8.1561x; 1.3030x over previous
//
#include <hip/hip_runtime.h>
#include <hip/hip_bf16.h>
#include <math.h>

#define Bb 1024
#define Tt 15
#define Ii 256
#define Hh 512
#define Ff 8
#define Gg 2048  // 4*Hh

typedef __attribute__((ext_vector_type(8))) short short8v;
typedef __attribute__((ext_vector_type(4))) float f32x4;

typedef const __attribute__((address_space(1))) void* gas_ptr;
typedef __attribute__((address_space(3))) void* las_ptr;

__device__ __forceinline__ float sigmoidf_(float x) { return 1.0f / (1.0f + expf(-x)); }
__device__ __forceinline__ float bf2f(unsigned short u) {
    return __uint_as_float(((unsigned int)u) << 16);
}
__device__ __forceinline__ unsigned short f2bf(float f) {
    unsigned int u = __float_as_uint(f);
    u += 0x7fffu + ((u >> 16) & 1u);   // RNE
    return (unsigned short)(u >> 16);
}

// ---------------- fp32 -> bf16 conversion (n8 = n/8) ----------------
__global__ __launch_bounds__(256) void cvt_kernel(const float* __restrict__ in,
                                                  unsigned short* __restrict__ out, int n8) {
    const int i = blockIdx.x * 256 + threadIdx.x;
    if (i < n8) {
        const float4 v0 = ((const float4*)in)[i * 2];
        const float4 v1 = ((const float4*)in)[i * 2 + 1];
        union { unsigned short u[8]; short8v v; } ob;
        ob.u[0] = f2bf(v0.x); ob.u[1] = f2bf(v0.y); ob.u[2] = f2bf(v0.z); ob.u[3] = f2bf(v0.w);
        ob.u[4] = f2bf(v1.x); ob.u[5] = f2bf(v1.y); ob.u[6] = f2bf(v1.z); ob.u[7] = f2bf(v1.w);
        *(short8v*)&out[(size_t)i * 8] = ob.v;
    }
}

// ---------------- MFMA step kernel ----------------
// grid = (Ff, h-blocks, Bb/128): blockIdx.x = f so linear%8 = f -> per-XCD weight residency.
// MODE 0: layer-0 LSTM step; MODE 1: layer-1 LSTM step; MODE 2: proj (+BN partial stats).
// Tile 128 (batch) x 128 (cols). 4 waves. BK=64. LDS: A,B tiles 16KB each (linear,
// XOR-swizzled via pre-swizzled global source for global_load_lds); epilogue aliases.
template<int MODE, bool FIRST>
__global__ __launch_bounds__(256) void step_mfma(
    const short* Xbf, const short* ysrc, short* ydst,
    const short* hsrc, short* hdst,
    const short* __restrict__ Wx, const short* __restrict__ Wh,
    const float* __restrict__ bias, float* __restrict__ cbuf,
    unsigned short* htmp, float* __restrict__ part, int t)
{
    const int f  = blockIdx.x;
    const int h0 = blockIdx.y * ((MODE == 2) ? 128 : 32);
    const int b0 = blockIdx.z * 128;
    const int tid = threadIdx.x;
    const int wave = tid >> 6, lane = tid & 63;
    const int wm = (wave >> 1) * 64, wn = (wave & 1) * 64;

    __shared__ __align__(16) char smem[32768 + 64];
    short* sA = (short*)smem;                 // [128][64] shorts, linear
    short* sB = sA + 8192;
    float* gt = (float*)smem;                 // [32][132] f32 epilogue chunk (alias)
    float* pr = (float*)(smem + 32768);

    f32x4 acc[4][4];
#pragma unroll
    for (int i = 0; i < 4; ++i)
#pragma unroll
        for (int j = 0; j < 4; ++j) acc[i][j] = (f32x4){0.f, 0.f, 0.f, 0.f};

    // staging geometry: per gload_lds instr: 64 lanes x 16B = 1KB = 8 rows of 128B
    const int srow8 = lane >> 3;                   // row-within-8
    const int csrc  = (lane & 7) ^ srow8;          // pre-swizzled source chunk
    const int frow  = lane & 15, fks = lane >> 4;  // fragment row / k-chunk

    auto phase = [&](const short* abase, long as, const short* wbase, int K, bool wgate) {
        for (int kb = 0; kb < K; kb += 64) {
#pragma unroll
            for (int i = 0; i < 4; ++i) {
                const int inst = wave * 4 + i;
                const int row = inst * 8 + srow8;
                const short* srcA = abase + (size_t)row * as + kb + csrc * 8;
                __builtin_amdgcn_global_load_lds((gas_ptr)(const void*)srcA,
                    (las_ptr)(void*)(sA + inst * 512), 16, 0, 0);
                const int wr = wgate ? ((row >> 5) * Hh + h0 + (row & 31)) : (h0 + row);
                const short* srcB = wbase + (size_t)wr * K + kb + csrc * 8;
                __builtin_amdgcn_global_load_lds((gas_ptr)(const void*)srcB,
                    (las_ptr)(void*)(sB + inst * 512), 16, 0, 0);
            }
            __syncthreads();
#pragma unroll
            for (int ks = 0; ks < 2; ++ks) {
                short8v av[4], bv[4];
#pragma unroll
                for (int i = 0; i < 4; ++i) {
                    const int r = wm + i * 16 + frow;
                    av[i] = *(const short8v*)&sA[r * 64 + (((fks + ks * 4) ^ (r & 7)) * 8)];
                }
#pragma unroll
                for (int j = 0; j < 4; ++j) {
                    const int r = wn + j * 16 + frow;
                    bv[j] = *(const short8v*)&sB[r * 64 + (((fks + ks * 4) ^ (r & 7)) * 8)];
                }
#pragma unroll
                for (int i = 0; i < 4; ++i)
#pragma unroll
                    for (int j = 0; j < 4; ++j)
                        acc[i][j] = __builtin_amdgcn_mfma_f32_16x16x32_bf16(av[i], bv[j], acc[i][j], 0, 0, 0);
            }
            __syncthreads();
        }
    };

    if (MODE == 0) {
        phase(Xbf + ((size_t)b0 * Tt + t) * Ii, (long)Tt * Ii, Wx + (size_t)f * Gg * Ii, Ii, true);
        if (!FIRST)
            phase(ysrc + (((size_t)f * Bb + b0) * Tt + (t - 1)) * Hh, (long)Tt * Hh,
                  Wh + (size_t)f * Gg * Hh, Hh, true);
    } else if (MODE == 1) {
        phase(ysrc + (((size_t)f * Bb + b0) * Tt + t) * Hh, (long)Tt * Hh,
              Wx + (size_t)f * Gg * Hh, Hh, true);
        if (!FIRST)
            phase(hsrc + ((size_t)f * Bb + b0) * Hh, (long)Hh, Wh + (size_t)f * Gg * Hh, Hh, true);
    } else {
        phase(hsrc + ((size_t)f * Bb + b0) * Hh, (long)Hh, Wx, Hh, false);
    }

    // ---- chunked epilogue: 4 chunks of 32 rows through gt [32][132] f32 ----
    if (MODE != 2) {
        const int hl = tid & 31, bg = tid >> 5;
        float bi[4];
#pragma unroll
        for (int g = 0; g < 4; ++g) bi[g] = bias[(size_t)f * Gg + g * Hh + h0 + hl];
#pragma unroll
        for (int ch = 0; ch < 4; ++ch) {
            if ((wave >> 1) == (ch >> 1)) {
                const int i0 = (ch & 1) * 2;
#pragma unroll
                for (int i2 = 0; i2 < 2; ++i2) {
                    const int i = i0 + i2;
#pragma unroll
                    for (int j = 0; j < 4; ++j)
#pragma unroll
                        for (int r = 0; r < 4; ++r)
                            gt[(i2 * 16 + (lane >> 4) * 4 + r) * 132 + wn + j * 16 + (lane & 15)] = acc[i][j][r];
                }
            }
            __syncthreads();
#pragma unroll
            for (int ii = 0; ii < 4; ++ii) {
                const int rl = bg * 4 + ii;
                const int b = b0 + ch * 32 + rl;
                const float gi = gt[rl * 132 +      hl] + bi[0];
                const float gf = gt[rl * 132 + 32 + hl] + bi[1];
                const float gg = gt[rl * 132 + 64 + hl] + bi[2];
                const float go = gt[rl * 132 + 96 + hl] + bi[3];
                const size_t cidx = ((size_t)f * Bb + b) * Hh + h0 + hl;
                const float cold = FIRST ? 0.f : cbuf[cidx];
                const float cn = sigmoidf_(gf) * cold + sigmoidf_(gi) * tanhf(gg);
                const float hv = sigmoidf_(go) * tanhf(cn);
                cbuf[cidx] = cn;
                const unsigned short hb = f2bf(hv);
                if (MODE == 0)
                    ((unsigned short*)ydst)[(((size_t)f * Bb + b) * Tt + t) * Hh + h0 + hl] = hb;
                else
                    ((unsigned short*)hdst)[cidx] = hb;
            }
            __syncthreads();
        }
    } else {
        const int rr2 = tid >> 3, cb = (tid & 7) * 16;
        float ssum = 0.f, ssq = 0.f;
#pragma unroll
        for (int ch = 0; ch < 4; ++ch) {
            if ((wave >> 1) == (ch >> 1)) {
                const int i0 = (ch & 1) * 2;
#pragma unroll
                for (int i2 = 0; i2 < 2; ++i2) {
                    const int i = i0 + i2;
#pragma unroll
                    for (int j = 0; j < 4; ++j)
#pragma unroll
                        for (int r = 0; r < 4; ++r)
                            gt[(i2 * 16 + (lane >> 4) * 4 + r) * 132 + wn + j * 16 + (lane & 15)] = acc[i][j][r];
                }
            }
            __syncthreads();
            const int b = b0 + ch * 32 + rr2;
            union { unsigned short u[8]; short8v v; } o1, o2;
#pragma unroll
            for (int u = 0; u < 8; ++u) {
                const unsigned short hb = f2bf(gt[rr2 * 132 + cb + u] + bias[h0 + cb + u]);
                const float hv = bf2f(hb);
                ssum += hv; ssq += hv * hv;
                o1.u[u] = hb;
            }
#pragma unroll
            for (int u = 0; u < 8; ++u) {
                const unsigned short hb = f2bf(gt[rr2 * 132 + cb + 8 + u] + bias[h0 + cb + 8 + u]);
                const float hv = bf2f(hb);
                ssum += hv; ssq += hv * hv;
                o2.u[u] = hb;
            }
            unsigned short* dst = htmp + (((size_t)f * Bb + b) * Tt + t) * Hh + h0 + cb;
            *(short8v*)dst = o1.v;
            *(short8v*)(dst + 8) = o2.v;
            __syncthreads();
        }
        // block partial (sum, sumsq) for BN stats
#pragma unroll
        for (int off2 = 32; off2 > 0; off2 >>= 1) {
            ssum += __shfl_down(ssum, off2);
            ssq  += __shfl_down(ssq,  off2);
        }
        if (lane == 0) { pr[wave * 2] = ssum; pr[wave * 2 + 1] = ssq; }
        __syncthreads();
        if (tid == 0) {
            float S = 0.f, Q = 0.f;
#pragma unroll
            for (int w = 0; w < 4; ++w) { S += pr[w * 2]; Q += pr[w * 2 + 1]; }
            const size_t pi = (((size_t)f * Tt + t) * 4 + blockIdx.y) * 8 + blockIdx.z;
            part[pi * 2] = S; part[pi * 2 + 1] = Q;
        }
    }
}

// ---------------- stats combine: mean / rsqrt(var) per (f,t) from 32 partials ----------------
__global__ void stats_combine_kernel(const float* __restrict__ part, float* __restrict__ stats)
{
    const int i = threadIdx.x;
    if (i < Ff * Tt) {
        float s = 0.f, q = 0.f;
        for (int j = 0; j < 32; ++j) { s += part[(i * 32 + j) * 2]; q += part[(i * 32 + j) * 2 + 1]; }
        const float n = (float)((size_t)Bb * Hh);
        const float mean = s / n;
        const float var  = q / n - mean * mean;
        stats[i * 2]     = mean;
        stats[i * 2 + 1] = rsqrtf(var + 1e-5f);
    }
}

// ---------------- Output: out[b,t,f] = sum_o relu(bn(htmp)) * A2[o] + c2 ----------------
__global__ __launch_bounds__(256) void out_kernel(
    const unsigned short* __restrict__ htmp, const float* __restrict__ stats,
    const float* __restrict__ gamma, const float* __restrict__ beta,
    const float* __restrict__ A2, const float* __restrict__ c2,
    float* __restrict__ out)
{
    const int wave = threadIdx.x >> 6;
    const int lane = threadIdx.x & 63;
    const size_t row = (size_t)blockIdx.x * 4 + wave;   // (f*B + b)*T + t
    const int t = (int)(row % Tt);
    const size_t fb = row / Tt;
    const int b = (int)(fb % Bb);
    const int f = (int)(fb / Bb);

    const float mean = stats[(f * Tt + t) * 2];
    const float inv  = stats[(f * Tt + t) * 2 + 1];
    const float ga = gamma[t], be = beta[t];
    const unsigned short* hrow = htmp + row * Hh;

    union { float4 f4; unsigned short u[8]; } hv;
    hv.f4 = *(const float4*)(hrow + lane * 8);
    const float4 a0 = *(const float4*)(A2 + lane * 8);
    const float4 a1 = *(const float4*)(A2 + lane * 8 + 4);
    const float a2v[8] = {a0.x, a0.y, a0.z, a0.w, a1.x, a1.y, a1.z, a1.w};

    float acc = 0.f;
#pragma unroll
    for (int j = 0; j < 8; ++j) {
        const float x = (bf2f(hv.u[j]) - mean) * inv * ga + be;
        acc += fmaxf(x, 0.f) * a2v[j];
    }
#pragma unroll
    for (int off = 32; off > 0; off >>= 1) acc += __shfl_down(acc, off);
    if (lane == 0) out[(size_t)b * Tt * Ff + (size_t)t * Ff + f] = acc + c2[0];
}

extern "C" void kernel_launch(void* const* d_in, const int* in_sizes, int n_in,
                              void* d_out, int out_size, void* d_ws, size_t ws_size,
                              hipStream_t stream) {
    const float* X     = (const float*)d_in[0];
    const float* Wih0  = (const float*)d_in[1];
    const float* Whh0  = (const float*)d_in[2];
    const float* b0p   = (const float*)d_in[3];
    const float* Wih1  = (const float*)d_in[4];
    const float* Whh1  = (const float*)d_in[5];
    const float* b1p   = (const float*)d_in[6];
    const float* A1    = (const float*)d_in[7];
    const float* c1v   = (const float*)d_in[8];
    const float* gamma = (const float*)d_in[9];
    const float* beta  = (const float*)d_in[10];
    const float* A2    = (const float*)d_in[11];
    const float* c2    = (const float*)d_in[12];
    float* out = (float*)d_out;

    // ---- workspace layout (bytes), total ~216 MiB ----
    char* ws = (char*)d_ws;
    size_t off = 0;
    short* Xbf    = (short*)(ws + off); off += (size_t)Bb * Tt * Ii * 2;
    short* Wih0bf = (short*)(ws + off); off += (size_t)Ff * Gg * Ii * 2;
    short* Whh0bf = (short*)(ws + off); off += (size_t)Ff * Gg * Hh * 2;
    short* Wih1bf = (short*)(ws + off); off += (size_t)Ff * Gg * Hh * 2;
    short* Whh1bf = (short*)(ws + off); off += (size_t)Ff * Gg * Hh * 2;
    short* A1bf   = (short*)(ws + off); off += (size_t)Hh * Hh * 2;
    short* ybuf   = (short*)(ws + off); off += (size_t)Ff * Bb * Tt * Hh * 2;
    short* h1A    = (short*)(ws + off); off += (size_t)Ff * Bb * Hh * 2;
    short* h1B    = (short*)(ws + off); off += (size_t)Ff * Bb * Hh * 2;
    float* cbuf   = (float*)(ws + off); off += (size_t)Ff * Bb * Hh * 4;
    float* part   = (float*)(ws + off); off += (size_t)Ff * Tt * 32 * 2 * 4;
    float* stats  = (float*)(ws + off); off += (size_t)Ff * Tt * 2 * 4;

    const dim3 blk(256);
    cvt_kernel<<<dim3((Bb * Tt * Ii / 8 + 255) / 256), blk, 0, stream>>>(X, (unsigned short*)Xbf, Bb * Tt * Ii / 8);
    cvt_kernel<<<dim3((Ff * Gg * Ii / 8 + 255) / 256), blk, 0, stream>>>(Wih0, (unsigned short*)Wih0bf, Ff * Gg * Ii / 8);
    cvt_kernel<<<dim3((Ff * Gg * Hh / 8 + 255) / 256), blk, 0, stream>>>(Whh0, (unsigned short*)Whh0bf, Ff * Gg * Hh / 8);
    cvt_kernel<<<dim3((Ff * Gg * Hh / 8 + 255) / 256), blk, 0, stream>>>(Wih1, (unsigned short*)Wih1bf, Ff * Gg * Hh / 8);
    cvt_kernel<<<dim3((Ff * Gg * Hh / 8 + 255) / 256), blk, 0, stream>>>(Whh1, (unsigned short*)Whh1bf, Ff * Gg * Hh / 8);
    cvt_kernel<<<dim3((Hh * Hh / 8 + 255) / 256), blk, 0, stream>>>(A1, (unsigned short*)A1bf, Hh * Hh / 8);

    const dim3 gstep(Ff, Hh / 32, Bb / 128);   // f fastest -> per-XCD weight residency
    const dim3 gproj(Ff, Hh / 128, Bb / 128);

    // layer 0: all timesteps, writes ybuf[f,b,t,:]
    for (int t = 0; t < Tt; ++t) {
        if (t == 0)
            step_mfma<0, true><<<gstep, blk, 0, stream>>>(Xbf, ybuf, ybuf, nullptr, nullptr,
                Wih0bf, Whh0bf, b0p, cbuf, nullptr, part, t);
        else
            step_mfma<0, false><<<gstep, blk, 0, stream>>>(Xbf, ybuf, ybuf, nullptr, nullptr,
                Wih0bf, Whh0bf, b0p, cbuf, nullptr, part, t);
    }

    // layer 1 + proj: step t reads ybuf slice t; proj overwrites ybuf slice t (stream-ordered)
    for (int t = 0; t < Tt; ++t) {
        short* hn = (t & 1) ? h1A : h1B;
        short* hp = (t & 1) ? h1B : h1A;
        if (t == 0)
            step_mfma<1, true><<<gstep, blk, 0, stream>>>(nullptr, ybuf, nullptr, hp, hn,
                Wih1bf, Whh1bf, b1p, cbuf, nullptr, part, t);
        else
            step_mfma<1, false><<<gstep, blk, 0, stream>>>(nullptr, ybuf, nullptr, hp, hn,
                Wih1bf, Whh1bf, b1p, cbuf, nullptr, part, t);
        step_mfma<2, false><<<gproj, blk, 0, stream>>>(nullptr, nullptr, nullptr, hn, nullptr,
            A1bf, nullptr, c1v, cbuf, (unsigned short*)ybuf, part, t);
    }

    stats_combine_kernel<<<dim3(1), dim3(128), 0, stream>>>(part, stats);
    out_kernel<<<dim3(Ff * Bb * Tt / 4), blk, 0, stream>>>((const unsigned short*)ybuf, stats,
        gamma, beta, A2, c2, out);
    (void)in_sizes; (void)n_in; (void)out_size; (void)ws_size;
}